// Round 4
// baseline (198.690 us; speedup 1.0000x reference)
//
#include <hip/hip_runtime.h>
#include <hip/hip_bf16.h>

// EdgeNet fused 2-layer MLP, MI355X (gfx950) — round 4 (R3 design, compile fixed).
//
// out[m][n2] = relu( sum_k2 relu( sum_k (parent[k]*child[m][k]) * W1[k2][k] + b1[k2] ) * W2[n2][k2] + b2[n2] )
//
// R2 post-mortem: HBM 26%, MfmaUtil 14%, VALU 12% -> latency-bound.
//   (a) launch_bounds(512,2) squeezed VGPRs to 64 => serialization/remat.
//   (b) phase-A HBM bursts don't overlap compute across lock-step blocks.
// R4: persistent blocks (grid=256, 1/CU), registers uncapped, and T14
// async-STAGE pipelining: tile t+1's child reads (16 x f32x4/lane) are issued
// immediately after tile t's LDS stage-write and stay in flight across all of
// tile t's compute => HBM never drains. Single 64 KiB LDS frag buffer (h
// overwrites x after layer 1, as in R2). 4 barriers/tile, no in-loop barriers.
//
// MFMA conventions (verified R1/R2, absmax 0.031):
//   A-frag: lane holds A[row = lane&15][k = 8*(lane>>4)+i], i=0..7
//   B-frag: lane holds B[k = 8*(lane>>4)+i][col = lane&15]
//   C/D  : lane holds C[row = 4*(lane>>4)+reg][col = lane&15]

typedef float f32x4 __attribute__((ext_vector_type(4)));
typedef short bf16x8 __attribute__((ext_vector_type(8)));
typedef unsigned int u32;
typedef u32 u32x4 __attribute__((ext_vector_type(4)));

__device__ __forceinline__ u32 pk2bf(float a, float b) {
    __hip_bfloat162 h2 = __float22bfloat162_rn(make_float2(a, b));
    u32 r;
    __builtin_memcpy(&r, &h2, 4);
    return r;
}

// Pack W (torch layout [n][k] row-major, f32) into per-lane MFMA fragment order:
// halfword[((kt*16 + nt)*64 + lane)*8 + i] = bf16(W[nt*16 + (lane&15)][kt*32 + 8*(lane>>4) + i])
__global__ __launch_bounds__(256) void pack_w_kernel(
    const float* __restrict__ W1, const float* __restrict__ W2,
    unsigned short* __restrict__ wp)
{
    int t = blockIdx.x * 256 + threadIdx.x;   // 0..16383
    int sel = t >> 13;
    int tt = t & 8191;
    int lane = tt & 63;
    int nt = (tt >> 6) & 15;
    int kt = tt >> 10;
    int n = nt * 16 + (lane & 15);
    int k0 = kt * 32 + 8 * (lane >> 4);
    const float* W = sel ? W2 : W1;
    const float* src = W + n * 256 + k0;
    f32x4 a = *(const f32x4*)src;
    f32x4 b = *(const f32x4*)(src + 4);
    u32x4 d;
    d.x = pk2bf(a.x, a.y);
    d.y = pk2bf(a.z, a.w);
    d.z = pk2bf(b.x, b.y);
    d.w = pk2bf(b.z, b.w);
    *(u32x4*)(wp + (size_t)t * 8) = d;
}

__global__ __launch_bounds__(512) void fused_mlp(
    const float* __restrict__ child, const float* __restrict__ parent,
    const float* __restrict__ b1, const float* __restrict__ b2,
    const unsigned short* __restrict__ w1p, const unsigned short* __restrict__ w2p,
    float* __restrict__ out, int n_rows)
{
    // 64 KiB fragment buffer: frag (mf, kt) at halfword (mf*8+kt)*512 + lane*8.
    // Holds x-frags during layer 1, h-frags during layer 2.
    __shared__ __align__(16) unsigned short xf[32768];
    __shared__ __align__(16) float par[256];
    __shared__ __align__(16) float bias[512];   // [0..255]=b1, [256..511]=b2

    const int tid = threadIdx.x;
    const int lane = tid & 63;
    const int w = tid >> 6;        // wave 0..7
    const int m16 = lane & 15;
    const int g = lane >> 4;

    if (tid < 256) { par[tid] = parent[tid]; bias[tid] = b1[tid]; }
    else           { bias[tid] = b2[tid - 256]; }
    __syncthreads();

    const int n_tiles = (n_rows + 127) >> 7;    // 1563

    // ---- T14 prefetch state: tile's child rows live in c[16] across compute
    f32x4 c[16];

    auto issue = [&](int tile) {
        long row = (long)tile * 128 + w * 16 + m16;
        long lim = (long)n_rows - 1;
        if (row > lim) row = lim;               // clamp: harmless duplicate reads
        const float* crow = child + row * 256;
        #pragma unroll
        for (int kt = 0; kt < 8; ++kt) {
            c[2 * kt]     = *(const f32x4*)(crow + kt * 32 + 8 * g);
            c[2 * kt + 1] = *(const f32x4*)(crow + kt * 32 + 8 * g + 4);
        }
    };

    issue(blockIdx.x);

    for (int tile = blockIdx.x; tile < n_tiles; tile += gridDim.x) {
        const int row0 = tile * 128;

        // ---- stage: multiply by parent, pack bf16, write x-frags to LDS ----
        #pragma unroll
        for (int kt = 0; kt < 8; ++kt) {
            f32x4 p0 = *(const f32x4*)&par[kt * 32 + 8 * g];
            f32x4 p1 = *(const f32x4*)&par[kt * 32 + 8 * g + 4];
            f32x4 c0 = c[2 * kt] * p0;
            f32x4 c1 = c[2 * kt + 1] * p1;
            u32x4 u;
            u.x = pk2bf(c0.x, c0.y);
            u.y = pk2bf(c0.z, c0.w);
            u.z = pk2bf(c1.x, c1.y);
            u.w = pk2bf(c1.z, c1.w);
            *(u32x4*)&xf[((w * 8 + kt) * 64 + lane) * 8] = u;
        }
        // ---- issue next tile's loads NOW: in flight across B/C/D ----
        issue(tile + gridDim.x);
        __syncthreads();

        // ---------------- layer 1: wave w computes n-slice [32w,32w+32) ----
        f32x4 acc1[2][8];
        #pragma unroll
        for (int j = 0; j < 2; ++j) {
            f32x4 bv = *(const f32x4*)&bias[(2 * w + j) * 16 + 4 * g];
            #pragma unroll
            for (int mf = 0; mf < 8; ++mf) acc1[j][mf] = bv;
        }
        #pragma unroll
        for (int kt = 0; kt < 8; ++kt) {
            bf16x8 a0 = *(const bf16x8*)(w1p + (size_t)((kt * 16 + 2 * w) * 64 + lane) * 8);
            bf16x8 a1 = *(const bf16x8*)(w1p + (size_t)((kt * 16 + 2 * w + 1) * 64 + lane) * 8);
            #pragma unroll
            for (int mf = 0; mf < 8; ++mf) {
                bf16x8 bfrag = *(const bf16x8*)&xf[((mf * 8 + kt) * 64 + lane) * 8];
                acc1[0][mf] = __builtin_amdgcn_mfma_f32_16x16x32_bf16(a0, bfrag, acc1[0][mf], 0, 0, 0);
                acc1[1][mf] = __builtin_amdgcn_mfma_f32_16x16x32_bf16(a1, bfrag, acc1[1][mf], 0, 0, 0);
            }
        }
        __syncthreads();   // all x-frag reads complete before overwrite

        // ---- relu + pack h, write h-frags into xf --------------------------
        // lane holds h[k2 = 32w + 16j + 4g + r][m = mf*16 + m16]
        //   -> frag (mf, kt2=w), lane' = 16*(2j + (g>>1)) + m16, halfword 4*(g&1) + r
        #pragma unroll
        for (int j = 0; j < 2; ++j) {
            #pragma unroll
            for (int mf = 0; mf < 8; ++mf) {
                f32x4 v = acc1[j][mf];
                v.x = fmaxf(v.x, 0.0f); v.y = fmaxf(v.y, 0.0f);
                v.z = fmaxf(v.z, 0.0f); v.w = fmaxf(v.w, 0.0f);
                u32* dst = (u32*)&xf[((mf * 8 + w) * 64 + 16 * (2 * j + (g >> 1)) + m16) * 8 + 4 * (g & 1)];
                dst[0] = pk2bf(v.x, v.y);
                dst[1] = pk2bf(v.z, v.w);
            }
        }
        __syncthreads();

        // ---------------- layer 2 + epilogue --------------------------------
        f32x4 acc2[2][8];
        #pragma unroll
        for (int j = 0; j < 2; ++j) {
            f32x4 bv = *(const f32x4*)&bias[256 + (2 * w + j) * 16 + 4 * g];
            #pragma unroll
            for (int mf = 0; mf < 8; ++mf) acc2[j][mf] = bv;
        }
        #pragma unroll
        for (int kt = 0; kt < 8; ++kt) {
            bf16x8 a0 = *(const bf16x8*)(w2p + (size_t)((kt * 16 + 2 * w) * 64 + lane) * 8);
            bf16x8 a1 = *(const bf16x8*)(w2p + (size_t)((kt * 16 + 2 * w + 1) * 64 + lane) * 8);
            #pragma unroll
            for (int mf = 0; mf < 8; ++mf) {
                bf16x8 hfrag = *(const bf16x8*)&xf[((mf * 8 + kt) * 64 + lane) * 8];
                acc2[0][mf] = __builtin_amdgcn_mfma_f32_16x16x32_bf16(a0, hfrag, acc2[0][mf], 0, 0, 0);
                acc2[1][mf] = __builtin_amdgcn_mfma_f32_16x16x32_bf16(a1, hfrag, acc2[1][mf], 0, 0, 0);
            }
        }

        // store: lane holds out[m = mf*16+m16][n2 = (2w+j)*16 + 4g + r]
        #pragma unroll
        for (int mf = 0; mf < 8; ++mf) {
            if (row0 + mf * 16 < n_rows) {     // wave-uniform (n_rows % 16 == 0)
                float* orow = out + (size_t)(row0 + mf * 16 + m16) * 256 + 4 * g;
                #pragma unroll
                for (int j = 0; j < 2; ++j) {
                    f32x4 v = acc2[j][mf];
                    v.x = fmaxf(v.x, 0.0f); v.y = fmaxf(v.y, 0.0f);
                    v.z = fmaxf(v.z, 0.0f); v.w = fmaxf(v.w, 0.0f);
                    *(f32x4*)(orow + (2 * w + j) * 16) = v;
                }
            }
        }
        __syncthreads();   // xf reads done before next tile's stage-write
    }
}

extern "C" void kernel_launch(void* const* d_in, const int* in_sizes, int n_in,
                              void* d_out, int out_size, void* d_ws, size_t ws_size,
                              hipStream_t stream) {
    const float* parent = (const float*)d_in[0];
    const float* child  = (const float*)d_in[1];
    const float* W1     = (const float*)d_in[2];
    const float* b1     = (const float*)d_in[3];
    const float* W2     = (const float*)d_in[4];
    const float* b2     = (const float*)d_in[5];
    float* out = (float*)d_out;

    unsigned short* wp = (unsigned short*)d_ws;   // [0..65535]=W1 frags, [65536..131071]=W2 frags
    const int n_rows = in_sizes[1] / 256;         // 200000

    pack_w_kernel<<<64, 256, 0, stream>>>(W1, W2, wp);
    fused_mlp<<<256, 512, 0, stream>>>(child, parent, b1, b2,
                                       wp, wp + 65536, out, n_rows);
}